// Round 1
// 2040.760 us; speedup vs baseline: 1.1321x; 1.1321x over previous
//
#include <hip/hip_runtime.h>
#include <math.h>

typedef __bf16 bf16_t;
typedef __bf16 bf16x8 __attribute__((ext_vector_type(8)));
typedef __bf16 bf16x4 __attribute__((ext_vector_type(4)));
typedef float  f32x4  __attribute__((ext_vector_type(4)));

// async global->LDS, 16B per lane; LDS dest must be wave-uniform base (+lane*16 by HW)
__device__ __forceinline__ void gll16(const void* g, void* l) {
    __builtin_amdgcn_global_load_lds((const __attribute__((address_space(1))) void*)g,
                                     (__attribute__((address_space(3))) void*)l, 16, 0, 0);
}

#define BAR()   do { __builtin_amdgcn_s_barrier(); asm volatile("" ::: "memory"); } while (0)
#define LGKM0() asm volatile("s_waitcnt lgkmcnt(0)" ::: "memory")
#define VMW(n)  asm volatile("s_waitcnt vmcnt(" #n ")" ::: "memory")

// ---------------- fp32 -> bf16 convert ----------------
__global__ void cvt_bf16(const float* __restrict__ in, bf16_t* __restrict__ out, long n) {
    long i = ((long)blockIdx.x * blockDim.x + threadIdx.x) * 4;
    long stride = (long)gridDim.x * blockDim.x * 4;
    for (; i < n; i += stride) {
        float4 v = *(const float4*)(in + i);
        bf16x4 o;
        o[0] = (bf16_t)v.x; o[1] = (bf16_t)v.y; o[2] = (bf16_t)v.z; o[3] = (bf16_t)v.w;
        *(bf16x4*)(out + i) = o;
    }
}

// ---------------- qkv bias vector: [q_bias, 0, v_bias] ----------------
__global__ void build_qkv_bias(const float* __restrict__ qb, const float* __restrict__ vb,
                               float* __restrict__ out) {
    int i = blockIdx.x * blockDim.x + threadIdx.x;   // 0..1535
    float v = 0.f;
    if (i < 512) v = qb[i];
    else if (i >= 1024) v = vb[i - 1024];
    out[i] = v;
}

// ---------------- CPB MLP: table[225][16] ----------------
__global__ void cpb_tab(const float* __restrict__ w1, const float* __restrict__ b1,
                        const float* __restrict__ w2, float* __restrict__ tab) {
    __shared__ float hid[512];
    int e = blockIdx.x;          // 0..224
    int ci = e / 15, cj = e % 15;
    int t = threadIdx.x;         // 0..511
    float a0 = (float)(ci - 7) * (8.0f / 7.0f);
    float a1 = (float)(cj - 7) * (8.0f / 7.0f);
    float s0 = (a0 > 0.f) ? 1.f : ((a0 < 0.f) ? -1.f : 0.f);
    float s1 = (a1 > 0.f) ? 1.f : ((a1 < 0.f) ? -1.f : 0.f);
    float t0 = s0 * log2f(fabsf(a0) + 1.f) * (1.f / 3.f);
    float t1 = s1 * log2f(fabsf(a1) + 1.f) * (1.f / 3.f);
    float hv = t0 * w1[t * 2] + t1 * w1[t * 2 + 1] + b1[t];
    hid[t] = hv > 0.f ? hv : 0.f;
    __syncthreads();
    int g = t >> 5, l = t & 31;  // 16 groups of 32 lanes
    float s = 0.f;
    for (int q = l; q < 512; q += 32) s += hid[q] * w2[g * 512 + q];
    s += __shfl_xor(s, 1);  s += __shfl_xor(s, 2);  s += __shfl_xor(s, 4);
    s += __shfl_xor(s, 8);  s += __shfl_xor(s, 16);
    if (l == 0) tab[e * 16 + g] = s;
}

// ---------------- expand to bias[16][64][64] with 16*sigmoid ----------------
__global__ void cpb_expand(const float* __restrict__ tab, float* __restrict__ biasx) {
    int idx = blockIdx.x * blockDim.x + threadIdx.x;  // 0..65535
    int h = idx >> 12;
    int rem = idx & 4095;
    int t1 = rem >> 6, t2 = rem & 63;
    int dh = (t1 >> 3) - (t2 >> 3) + 7;
    int dw = (t1 & 7) - (t2 & 7) + 7;
    float v = tab[(dh * 15 + dw) * 16 + h];
    biasx[idx] = 16.0f / (1.0f + __expf(-v));
}

// ======================================================================
// 256x256 tile, BK=64, 8 waves, 8-phase-style schedule (4 phases/K-tile),
// counted vmcnt(4), st-swizzled LDS, XCD-swizzled 1D grid.
// C[M,N] = A[M,K] @ B[N,K]^T + bias[N]
// ======================================================================
#define MMAQ(qm, qn, bfr)                                                          \
  do {                                                                             \
    __builtin_amdgcn_s_setprio(1);                                                 \
    _Pragma("unroll") for (int i_ = 0; i_ < 4; ++i_)                               \
      _Pragma("unroll") for (int j_ = 0; j_ < 2; ++j_)                             \
        _Pragma("unroll") for (int kk_ = 0; kk_ < 2; ++kk_)                        \
          acc[(qm)*4 + i_][(qn)*2 + j_] = __builtin_amdgcn_mfma_f32_16x16x32_bf16( \
              a[i_][kk_], bfr[j_][kk_], acc[(qm)*4 + i_][(qn)*2 + j_], 0, 0, 0);   \
    __builtin_amdgcn_s_setprio(0);                                                 \
  } while (0)

template <int OUT_BF16>
__global__ __launch_bounds__(512, 2) void gemm256(
    const bf16_t* __restrict__ A, const bf16_t* __restrict__ B,
    const float* __restrict__ bias, void* __restrict__ Cout,
    int N, int K, int nTN) {
    // LDS: 2 bufs x (A 32KB + B 32KB) = 128 KiB
    __shared__ __attribute__((aligned(16))) char lds[131072];
    const int tid = threadIdx.x;
    const int wid = tid >> 6;
    const int ln  = tid & 63;
    const int quad = ln >> 4, l15 = ln & 15;
    const int wm2 = wid >> 2, wn4 = wid & 3;   // 2 M-waves x 4 N-waves

    // bijective XCD swizzle (gridDim.x % 8 == 0), bn fast within an XCD chunk
    const int nwg = gridDim.x;
    const int bid = blockIdx.x;
    const int swz = (bid & 7) * (nwg >> 3) + (bid >> 3);
    const int bm = swz / nTN, bn = swz % nTN;
    const long arow0 = (long)bm * 256;
    const int  bcol0 = bn * 256;
    const int  nt = K >> 6;                    // K-tiles of 64

    // staging: per-lane pre-swizzled global source, linear LDS dest.
    // lane covers phys row (wid*16 + q*8 + ln/8), 16B chunk (ln&7);
    // content for phys chunk p at row r is logical chunk p ^ (r&7)  (st swizzle)
    const int srow = wid * 16 + (ln >> 3);
    const int scol = ((ln & 7) ^ (ln >> 3)) * 8;           // elements
    const bf16_t* gA = A + (arow0 + srow) * (long)K + scol;
    const bf16_t* gB = B + ((long)bcol0 + srow) * (long)K + scol;
    const long rK8 = (long)K * 8;                          // +8 rows
    const int ldsw = wid * 2048;

    // ds_read byte-col: (kk*64 + quad*16) ^ ((row&7)<<4);  row&7 == l15&7
    const int cb0 = (quad * 16) ^ ((l15 & 7) << 4);

    f32x4 acc[8][4] = {};
    bf16x8 a[4][2], b0[2][2], b1[2][2];

    auto stageA = [&](int v, int hi) {
        char* d = &lds[((v & 1) << 16) + (hi << 14) + ldsw];
        const bf16_t* s = gA + (long)(hi * 128) * K + v * 64;
        gll16(s, d);
        gll16(s + rK8, d + 1024);
    };
    auto stageB = [&](int v, int hi) {
        char* d = &lds[((v & 1) << 16) + 32768 + (hi << 14) + ldsw];
        const bf16_t* s = gB + (long)(hi * 128) * K + v * 64;
        gll16(s, d);
        gll16(s + rK8, d + 1024);
    };
    auto ldA = [&](int buf, int qm) {
#pragma unroll
        for (int i = 0; i < 4; ++i) {
            const char* p = &lds[(buf << 16) + (wm2 * 128 + qm * 64 + i * 16 + l15) * 128];
            a[i][0] = *(const bf16x8*)(p + cb0);
            a[i][1] = *(const bf16x8*)(p + (cb0 ^ 64));
        }
    };
    auto ldB = [&](bf16x8 (&bf)[2][2], int buf, int qn) {
#pragma unroll
        for (int j = 0; j < 2; ++j) {
            const char* p = &lds[(buf << 16) + 32768 + (wn4 * 64 + qn * 32 + j * 16 + l15) * 128];
            bf[j][0] = *(const bf16x8*)(p + cb0);
            bf[j][1] = *(const bf16x8*)(p + (cb0 ^ 64));
        }
    };

    // prologue: all 4 units of tile 0 + B units of tile 1 (A(1) staged in P1/P2 of tile 0)
    stageA(0, 0); stageA(0, 1); stageB(0, 0); stageB(0, 1);
    if (nt > 1) { stageB(1, 0); stageB(1, 1); VMW(4); }
    else        { VMW(0); }
    BAR();

    for (int u = 0; u < nt; ++u) {
        const int buf = u & 1;
        // P1: quadrant (0,0); stage A_lo(u+1) -> other buf (free since P3(u-1))
        ldA(buf, 0); ldB(b0, buf, 0);
        if (u + 1 < nt) stageA(u + 1, 0);
        BAR(); LGKM0();
        MMAQ(0, 0, b0);
        BAR();
        // P2: quadrant (0,1); stage A_hi(u+1)
        ldB(b1, buf, 1);
        if (u + 1 < nt) stageA(u + 1, 1);
        BAR(); LGKM0();
        MMAQ(0, 1, b1);
        BAR();
        // P3: quadrant (1,1); stage B_lo(u+2) -> this buf (B_lo last read at P2)
        ldA(buf, 1);
        if (u + 2 < nt) stageB(u + 2, 0);
        BAR(); LGKM0();
        MMAQ(1, 1, b1);
        BAR();
        // P4: quadrant (1,0) (a from P3, b0 from P1); stage B_hi(u+2)
        if (u + 2 < nt) stageB(u + 2, 1);
        BAR();
        MMAQ(1, 0, b0);
        // counted wait: tile u+1's 4 units are the oldest 8 loads; keep B(u+2) in flight
        if (u + 2 < nt) { VMW(4); } else { VMW(0); }
        BAR();
    }

    // epilogue: C += bias, write
#pragma unroll
    for (int qm = 0; qm < 2; ++qm)
#pragma unroll
    for (int i = 0; i < 4; ++i) {
        const long rb = arow0 + wm2 * 128 + qm * 64 + i * 16 + quad * 4;
#pragma unroll
        for (int qn = 0; qn < 2; ++qn)
#pragma unroll
        for (int j = 0; j < 2; ++j) {
            const int c = bcol0 + wn4 * 64 + qn * 32 + j * 16 + l15;
            const float bv = bias[c];
            const f32x4 v4 = acc[qm * 4 + i][qn * 2 + j];
#pragma unroll
            for (int r = 0; r < 4; ++r) {
                float v = v4[r] + bv;
                if (OUT_BF16)
                    ((bf16_t*)Cout)[(rb + r) * (long)N + c] = (bf16_t)v;
                else
                    ((float*)Cout)[(rb + r) * (long)N + c] = v;
            }
        }
    }
}

// ---------------- per-(window,head) attention, 1 wave ----------------
__device__ __forceinline__ void load_norm_row(const bf16_t* g, bf16_t* lds_row) {
    bf16x8 t[4];
#pragma unroll
    for (int i = 0; i < 4; ++i) t[i] = *(const bf16x8*)(g + i * 8);
    float f[32];
    float ss = 0.f;
#pragma unroll
    for (int i = 0; i < 4; ++i)
#pragma unroll
        for (int e = 0; e < 8; ++e) {
            float v = (float)t[i][e];
            f[i * 8 + e] = v;
            ss += v * v;
        }
    float inv = rsqrtf(ss);
#pragma unroll
    for (int i = 0; i < 4; ++i) {
        bf16x8 o;
#pragma unroll
        for (int e = 0; e < 8; ++e) o[e] = (bf16_t)(f[i * 8 + e] * inv);
        *(bf16x8*)(lds_row + i * 8) = o;
    }
}

__global__ __launch_bounds__(64) void attn64(
    const bf16_t* __restrict__ qkv,    // [B*64, 1536]
    const float* __restrict__ mask,    // [256,64,64]
    const float* __restrict__ biasx,   // [16,64,64]
    const float* __restrict__ lsc,     // [16]
    bf16_t* __restrict__ outa) {       // [B*64, 512]
    __shared__ __attribute__((aligned(16))) bf16_t qs[64 * 32];
    __shared__ __attribute__((aligned(16))) bf16_t ks[64 * 32];
    __shared__ __attribute__((aligned(16))) bf16_t vt[32 * 64];
    __shared__ __attribute__((aligned(16))) bf16_t ps[64 * 64];
    const int b = blockIdx.x;
    const int h = blockIdx.y;
    const int ln = threadIdx.x;
    const int quad = ln >> 4, l15 = ln & 15;
    const long rowbase = (long)b * 64 * 1536;
    const bf16_t* qrow = qkv + rowbase + ln * 1536 + h * 32;

    load_norm_row(qrow, &qs[ln * 32]);
    load_norm_row(qrow + 512, &ks[ln * 32]);
    {   // V transposed: vt[n][k=token]
        const bf16_t* vr = qrow + 1024;
        bf16x8 t[4];
#pragma unroll
        for (int i = 0; i < 4; ++i) t[i] = *(const bf16x8*)(vr + i * 8);
#pragma unroll
        for (int i = 0; i < 4; ++i)
#pragma unroll
            for (int e = 0; e < 8; ++e) vt[(i * 8 + e) * 64 + ln] = t[i][e];
    }
    __syncthreads();

    // S = qn @ kn^T  (4x4 tiles of 16x16, K=32)
    f32x4 sa[4][4] = {};
    {
        bf16x8 af[4], bfr[4];
#pragma unroll
        for (int i = 0; i < 4; ++i)
            af[i] = *(const bf16x8*)&qs[(i * 16 + l15) * 32 + quad * 8];
#pragma unroll
        for (int j = 0; j < 4; ++j)
            bfr[j] = *(const bf16x8*)&ks[(j * 16 + l15) * 32 + quad * 8];
#pragma unroll
        for (int i = 0; i < 4; ++i)
#pragma unroll
            for (int j = 0; j < 4; ++j)
                sa[i][j] = __builtin_amdgcn_mfma_f32_16x16x32_bf16(af[i], bfr[j], sa[i][j], 0, 0, 0);
    }

    const float scale = __expf(fminf(lsc[h], 4.60517019f));
    const float* mrow = mask + (long)(b & 255) * 4096;
    const float* brow = biasx + h * 4096;

    // logits (C/D layout: row = i*16+quad*4+r, col = j*16+l15)
#pragma unroll
    for (int i = 0; i < 4; ++i)
#pragma unroll
        for (int j = 0; j < 4; ++j)
#pragma unroll
            for (int r = 0; r < 4; ++r) {
                int rr = i * 16 + quad * 4 + r;
                int cc = j * 16 + l15;
                sa[i][j][r] = sa[i][j][r] * scale + brow[rr * 64 + cc] + mrow[rr * 64 + cc];
            }

    // row softmax: reduce across 16 lanes (same quad) x 4 j-tiles
    float rmax[4][4], rsum[4][4];
#pragma unroll
    for (int i = 0; i < 4; ++i)
#pragma unroll
        for (int r = 0; r < 4; ++r) {
            float m = sa[i][0][r];
#pragma unroll
            for (int j = 1; j < 4; ++j) m = fmaxf(m, sa[i][j][r]);
            m = fmaxf(m, __shfl_xor(m, 1));
            m = fmaxf(m, __shfl_xor(m, 2));
            m = fmaxf(m, __shfl_xor(m, 4));
            m = fmaxf(m, __shfl_xor(m, 8));
            rmax[i][r] = m;
        }
#pragma unroll
    for (int i = 0; i < 4; ++i)
#pragma unroll
        for (int r = 0; r < 4; ++r) {
            float s = 0.f;
#pragma unroll
            for (int j = 0; j < 4; ++j) {
                float e = __expf(sa[i][j][r] - rmax[i][r]);
                sa[i][j][r] = e;
                s += e;
            }
            s += __shfl_xor(s, 1);
            s += __shfl_xor(s, 2);
            s += __shfl_xor(s, 4);
            s += __shfl_xor(s, 8);
            rsum[i][r] = s;
        }
#pragma unroll
    for (int i = 0; i < 4; ++i)
#pragma unroll
        for (int j = 0; j < 4; ++j)
#pragma unroll
            for (int r = 0; r < 4; ++r) {
                float p = sa[i][j][r] / rsum[i][r];
                ps[(i * 16 + quad * 4 + r) * 64 + j * 16 + l15] = (bf16_t)p;
            }
    __syncthreads();

    // O = P @ V : P[64,64] (A layout), Vt[n][k] (B layout), 2 k-steps, 2 n-tiles
    f32x4 oa[4][2] = {};
#pragma unroll
    for (int kst = 0; kst < 2; ++kst) {
        bf16x8 pf[4], vf[2];
#pragma unroll
        for (int i = 0; i < 4; ++i)
            pf[i] = *(const bf16x8*)&ps[(i * 16 + l15) * 64 + kst * 32 + quad * 8];
#pragma unroll
        for (int n2 = 0; n2 < 2; ++n2)
            vf[n2] = *(const bf16x8*)&vt[(n2 * 16 + l15) * 64 + kst * 32 + quad * 8];
#pragma unroll
        for (int i = 0; i < 4; ++i)
#pragma unroll
            for (int n2 = 0; n2 < 2; ++n2)
                oa[i][n2] = __builtin_amdgcn_mfma_f32_16x16x32_bf16(pf[i], vf[n2], oa[i][n2], 0, 0, 0);
    }
#pragma unroll
    for (int i = 0; i < 4; ++i)
#pragma unroll
        for (int n2 = 0; n2 < 2; ++n2)
#pragma unroll
            for (int r = 0; r < 4; ++r) {
                long row = (long)b * 64 + i * 16 + quad * 4 + r;
                int col = h * 32 + n2 * 16 + l15;
                outa[row * 512 + col] = (bf16_t)oa[i][n2][r];
            }
}

extern "C" void kernel_launch(void* const* d_in, const int* in_sizes, int n_in,
                              void* d_out, int out_size, void* d_ws, size_t ws_size,
                              hipStream_t stream) {
    const float* x           = (const float*)d_in[0];   // [4096,64,512]
    const float* mask        = (const float*)d_in[1];   // [256,64,64]
    const float* qkv_w       = (const float*)d_in[2];   // [1536,512]
    const float* q_bias      = (const float*)d_in[3];   // [512]
    const float* v_bias      = (const float*)d_in[4];   // [512]
    const float* logit_scale = (const float*)d_in[5];   // [16]
    const float* cpb_w1      = (const float*)d_in[6];   // [512,2]
    const float* cpb_b1      = (const float*)d_in[7];   // [512]
    const float* cpb_w2      = (const float*)d_in[8];   // [16,512]
    const float* proj_w      = (const float*)d_in[9];   // [512,512]
    const float* proj_b      = (const float*)d_in[10];  // [512]
    float* out = (float*)d_out;

    char* w = (char*)d_ws;
    bf16_t* qkvb = (bf16_t*)w;          w += (size_t)402653184 * 2;  // [262144,1536] bf16
    bf16_t* xb   = (bf16_t*)w;          w += (size_t)134217728 * 2;  // x bf16 / attn out (aliased)
    bf16_t* attn_o = xb;
    bf16_t* qkvw_b = (bf16_t*)w;        w += (size_t)786432 * 2;
    bf16_t* projw_b = (bf16_t*)w;       w += (size_t)262144 * 2;
    float* biasx = (float*)w;           w += (size_t)65536 * 4;
    float* qkv_bias = (float*)w;        w += (size_t)1536 * 4;
    float* tab = (float*)w;             w += (size_t)3600 * 4;

    cvt_bf16<<<8192, 256, 0, stream>>>(x, xb, 134217728L);
    cvt_bf16<<<768, 256, 0, stream>>>(qkv_w, qkvw_b, 786432L);
    cvt_bf16<<<256, 256, 0, stream>>>(proj_w, projw_b, 262144L);
    build_qkv_bias<<<6, 256, 0, stream>>>(q_bias, v_bias, qkv_bias);
    cpb_tab<<<225, 512, 0, stream>>>(cpb_w1, cpb_b1, cpb_w2, tab);
    cpb_expand<<<64, 1024, 0, stream>>>(tab, biasx);

    // QKV GEMM: [262144,1536] = xb[262144,512] @ qkvw_b[1536,512]^T ; 1024x6 tiles
    gemm256<1><<<dim3(6144), 512, 0, stream>>>(xb, qkvw_b, qkv_bias, qkvb, 1536, 512, 6);

    dim3 ga(4096, 16);
    attn64<<<ga, 64, 0, stream>>>(qkvb, mask, biasx, logit_scale, attn_o);

    // proj GEMM: [262144,512] = attn_o @ projw_b[512,512]^T ; 1024x2 tiles
    gemm256<0><<<dim3(2048), 512, 0, stream>>>(attn_o, projw_b, proj_b, out, 512, 512, 2);
}